// Round 2
// baseline (92.066 us; speedup 1.0000x reference)
//
#include <hip/hip_runtime.h>
#include <math.h>

// Problem constants (match reference setup)
#define NUM_EGO    32
#define AGENTS_PER 128
#define T_TOTAL    34
#define H_OFF      4
#define TN         30           // T_TOTAL - H
#define SCALE      1.9f         // LEAST_MIN_TTC / DT = 0.95 / 0.5

// One block per ego. 128 threads = one per agent in the ego's block.
// Thread loops over all 30 timesteps; block reduces "any collision" and
// writes out[b] exactly once. Single dispatch, no init kernel needed.
__global__ __launch_bounds__(AGENTS_PER) void ttc_fused(
    const float* __restrict__ posg,     // (N, 34, 2)
    const float* __restrict__ headg,    // (N, 34)
    const float* __restrict__ boxg,     // (N, 4)
    const int*   __restrict__ validg,   // (N, 34) 0/1
    const int*   __restrict__ ptrg,     // (33,)
    float* __restrict__ out)            // (32,)
{
    const int b = blockIdx.x;

    // LDS: per-t ego state. 12 floats per t: ex,ey,ce,se, 4 corners (x,y)
    __shared__ float s_ex[TN], s_ey[TN], s_ce[TN], s_se[TN];
    __shared__ float s_cx[TN][4], s_cy[TN][4];
    __shared__ int   s_evalid[TN];
    __shared__ float s_ebox[4];
    __shared__ int   s_e0;
    __shared__ int   s_any;

    if (threadIdx.x == 0) {
        s_any = 0;
        int e0 = ptrg[b];
        s_e0 = e0;
        s_ebox[0] = boxg[e0 * 4 + 0];
        s_ebox[1] = boxg[e0 * 4 + 1];
        s_ebox[2] = boxg[e0 * 4 + 2];
        s_ebox[3] = boxg[e0 * 4 + 3];
    }
    __syncthreads();

    const int e0 = s_e0;

    // Threads 0..29 each stage ego pose for one timestep.
    if (threadIdx.x < TN) {
        const int t  = threadIdx.x;
        const int tt = t + H_OFF;
        s_evalid[t] = validg[e0 * T_TOTAL + tt];
        float px1 = posg[(e0 * T_TOTAL + tt) * 2 + 0];
        float py1 = posg[(e0 * T_TOTAL + tt) * 2 + 1];
        float px0 = posg[(e0 * T_TOTAL + tt - 1) * 2 + 0];
        float py0 = posg[(e0 * T_TOTAL + tt - 1) * 2 + 1];
        float ex = px1 + SCALE * (px1 - px0);
        float ey = py1 + SCALE * (py1 - py0);
        float yaw = headg[e0 * T_TOTAL + tt];
        float c = cosf(yaw), s = sinf(yaw);
        s_ex[t] = ex; s_ey[t] = ey; s_ce[t] = c; s_se[t] = s;
        float f  = s_ebox[0];
        float r  = s_ebox[1];
        float l  = s_ebox[2];
        float rt = s_ebox[3];
        float lxs[4] = { f,  f, -r, -r };
        float lys[4] = { l, -rt, -rt,  l };
        #pragma unroll
        for (int k = 0; k < 4; ++k) {
            s_cx[t][k] = lxs[k] * c - lys[k] * s + ex;
            s_cy[t][k] = lxs[k] * s + lys[k] * c + ey;
        }
    }
    __syncthreads();

    const int n = e0 + threadIdx.x;      // this thread's agent
    const bool is_ego = (threadIdx.x == 0);

    // Agent box (constant over t)
    const float af  = boxg[n * 4 + 0];
    const float ar  = boxg[n * 4 + 1];
    const float al  = boxg[n * 4 + 2];
    const float art = boxg[n * 4 + 3];
    const float ef  = s_ebox[0], er = s_ebox[1], el = s_ebox[2], ert = s_ebox[3];

    // agent local corner offsets
    const float lxs[4] = { af,  af, -ar, -ar };
    const float lys[4] = { al, -art, -art,  al };

    bool any = false;

    // prime previous position (tt-1 for t=0 is H_OFF-1)
    float ppx = posg[(n * T_TOTAL + H_OFF - 1) * 2 + 0];
    float ppy = posg[(n * T_TOTAL + H_OFF - 1) * 2 + 1];

    for (int t = 0; t < TN; ++t) {
        const int tt = t + H_OFF;
        float px1 = posg[(n * T_TOTAL + tt) * 2 + 0];
        float py1 = posg[(n * T_TOTAL + tt) * 2 + 1];
        float ax = px1 + SCALE * (px1 - ppx);
        float ay = py1 + SCALE * (py1 - ppy);
        ppx = px1; ppy = py1;

        if (is_ego || !s_evalid[t]) continue;
        if (validg[n * T_TOTAL + tt] == 0) continue;

        float ayaw = headg[n * T_TOTAL + tt];
        float ca = cosf(ayaw), sa = sinf(ayaw);

        const float ex = s_ex[t], ey = s_ey[t];
        const float ce = s_ce[t], se = s_se[t];

        // L1: ego corners in agent frame vs agent box
        float L1 = 0.0f;
        #pragma unroll
        for (int k = 0; k < 4; ++k) {
            float dx = s_cx[t][k] - ax;
            float dy = s_cy[t][k] - ay;
            float lx =  dx * ca + dy * sa;
            float ly = -dx * sa + dy * ca;
            float lo = fminf(fmaxf(af - lx, 0.0f), fmaxf(ar + lx, 0.0f));
            float la = fminf(fmaxf(al - ly, 0.0f), fmaxf(art + ly, 0.0f));
            L1 = fmaxf(L1, fminf(lo, la));
        }

        // L2: agent corners in ego frame vs ego box
        float L2 = 0.0f;
        #pragma unroll
        for (int k = 0; k < 4; ++k) {
            float cxw = lxs[k] * ca - lys[k] * sa + ax;
            float cyw = lxs[k] * sa + lys[k] * ca + ay;
            float dx = cxw - ex;
            float dy = cyw - ey;
            float lx =  dx * ce + dy * se;
            float ly = -dx * se + dy * ce;
            float lo = fminf(fmaxf(ef - lx, 0.0f), fmaxf(er + lx, 0.0f));
            float la = fminf(fmaxf(el - ly, 0.0f), fmaxf(ert + ly, 0.0f));
            L2 = fmaxf(L2, fminf(lo, la));
        }

        any |= (fmaxf(L1, L2) > 0.0f);
    }

    if (any) s_any = 1;      // benign multi-writer of identical value
    __syncthreads();
    if (threadIdx.x == 0) {
        out[b] = s_any ? 0.0f : 1.0f;
    }
}

extern "C" void kernel_launch(void* const* d_in, const int* in_sizes, int n_in,
                              void* d_out, int out_size, void* d_ws, size_t ws_size,
                              hipStream_t stream) {
    const float* posg   = (const float*)d_in[0];  // infer_position (N,34,2)
    const float* headg  = (const float*)d_in[1];  // infer_heading  (N,34)
    const float* boxg   = (const float*)d_in[2];  // box            (N,4)
    const int*   validg = (const int*)  d_in[3];  // infer_valid_mask (N,34)
    // d_in[4] = batch (unused: implied by ptr blocks)
    const int*   ptrg   = (const int*)  d_in[5];  // ptr (33,)
    float* out = (float*)d_out;

    ttc_fused<<<NUM_EGO, AGENTS_PER, 0, stream>>>(posg, headg, boxg, validg, ptrg, out);
}

// Round 3
// 71.911 us; speedup vs baseline: 1.2803x; 1.2803x over previous
//
#include <hip/hip_runtime.h>
#include <math.h>

// Problem constants (match reference setup)
#define NUM_EGO    32
#define AGENTS_PER 128
#define T_TOTAL    34
#define H_OFF      4
#define TN         30           // T_TOTAL - H
#define SCALE      1.9f         // LEAST_MIN_TTC / DT = 0.95 / 0.5
#define NSLICE     8            // time slices per ego block
#define PER_SLICE  4            // ceil(TN / NSLICE) timesteps per thread

// One block per ego. 1024 threads = 128 agents x 8 time-slices.
// Thread (a, s) handles timesteps t = s, s+8, s+16, s+24 (skip t>=30).
// All global loads are issued up front, branch-free; validity is applied
// as a mask at the end. Block reduces "any collision" in LDS; thread 0
// writes out[b] exactly once. Single dispatch, no init kernel, no races.
__global__ __launch_bounds__(AGENTS_PER * NSLICE) void ttc_fused(
    const float* __restrict__ posg,     // (N, 34, 2)
    const float* __restrict__ headg,    // (N, 34)
    const float* __restrict__ boxg,     // (N, 4)
    const int*   __restrict__ validg,   // (N, 34) 0/1
    const int*   __restrict__ ptrg,     // (33,)
    float* __restrict__ out)            // (32,)
{
    const int b = blockIdx.x;
    const int a = threadIdx.x & (AGENTS_PER - 1);   // agent slot 0..127
    const int s = threadIdx.x >> 7;                 // time slice 0..7

    // LDS: per-t ego state
    __shared__ float s_ex[TN], s_ey[TN], s_ce[TN], s_se[TN];
    __shared__ float s_cx[TN][4], s_cy[TN][4];
    __shared__ int   s_evalid[TN];
    __shared__ float s_ebox[4];
    __shared__ int   s_e0;
    __shared__ int   s_any;

    if (threadIdx.x == 0) {
        s_any = 0;
        int e0 = ptrg[b];
        s_e0 = e0;
        s_ebox[0] = boxg[e0 * 4 + 0];
        s_ebox[1] = boxg[e0 * 4 + 1];
        s_ebox[2] = boxg[e0 * 4 + 2];
        s_ebox[3] = boxg[e0 * 4 + 3];
    }
    __syncthreads();

    const int e0 = s_e0;

    // Threads 0..29 stage ego pose/corners for one timestep each.
    if (threadIdx.x < TN) {
        const int t  = threadIdx.x;
        const int tt = t + H_OFF;
        s_evalid[t] = validg[e0 * T_TOTAL + tt];
        float2 p1 = *(const float2*)&posg[(e0 * T_TOTAL + tt) * 2];
        float2 p0 = *(const float2*)&posg[(e0 * T_TOTAL + tt - 1) * 2];
        float ex = p1.x + SCALE * (p1.x - p0.x);
        float ey = p1.y + SCALE * (p1.y - p0.y);
        float yaw = headg[e0 * T_TOTAL + tt];
        float c = cosf(yaw), sn = sinf(yaw);
        s_ex[t] = ex; s_ey[t] = ey; s_ce[t] = c; s_se[t] = sn;
        float f  = s_ebox[0];
        float r  = s_ebox[1];
        float l  = s_ebox[2];
        float rt = s_ebox[3];
        float lxs[4] = { f,  f, -r, -r };
        float lys[4] = { l, -rt, -rt,  l };
        #pragma unroll
        for (int k = 0; k < 4; ++k) {
            s_cx[t][k] = lxs[k] * c - lys[k] * sn + ex;
            s_cy[t][k] = lxs[k] * sn + lys[k] * c + ey;
        }
    }
    __syncthreads();

    const int n = e0 + a;                 // this thread's agent
    const bool not_ego = (a != 0);

    // ---- Issue ALL global loads up front, branch-free ----
    float2 p1v[PER_SLICE], p0v[PER_SLICE];
    float  yawv[PER_SLICE];
    int    avalid[PER_SLICE];
    #pragma unroll
    for (int i = 0; i < PER_SLICE; ++i) {
        int t  = s + NSLICE * i;          // 0..31
        int tc = (t < TN) ? t : (TN - 1); // clamp for safe addressing
        int tt = tc + H_OFF;
        p1v[i] = *(const float2*)&posg[(n * T_TOTAL + tt) * 2];
        p0v[i] = *(const float2*)&posg[(n * T_TOTAL + tt - 1) * 2];
        yawv[i] = headg[n * T_TOTAL + tt];
        avalid[i] = validg[n * T_TOTAL + tt];
    }
    const float af  = boxg[n * 4 + 0];
    const float ar  = boxg[n * 4 + 1];
    const float al  = boxg[n * 4 + 2];
    const float art = boxg[n * 4 + 3];
    const float ef  = s_ebox[0], er = s_ebox[1], el = s_ebox[2], ert = s_ebox[3];

    const float alx[4] = { af,  af, -ar, -ar };
    const float aly[4] = { al, -art, -art,  al };

    bool any = false;

    #pragma unroll
    for (int i = 0; i < PER_SLICE; ++i) {
        int t = s + NSLICE * i;
        if (t >= TN) break;

        float ax = p1v[i].x + SCALE * (p1v[i].x - p0v[i].x);
        float ay = p1v[i].y + SCALE * (p1v[i].y - p0v[i].y);
        float ca = cosf(yawv[i]), sa = sinf(yawv[i]);

        const float ex = s_ex[t], ey = s_ey[t];
        const float ce = s_ce[t], se = s_se[t];

        // L1: ego corners in agent frame vs agent box
        float L1 = 0.0f;
        #pragma unroll
        for (int k = 0; k < 4; ++k) {
            float dx = s_cx[t][k] - ax;
            float dy = s_cy[t][k] - ay;
            float lx =  dx * ca + dy * sa;
            float ly = -dx * sa + dy * ca;
            float lo = fminf(fmaxf(af - lx, 0.0f), fmaxf(ar + lx, 0.0f));
            float la = fminf(fmaxf(al - ly, 0.0f), fmaxf(art + ly, 0.0f));
            L1 = fmaxf(L1, fminf(lo, la));
        }

        // L2: agent corners in ego frame vs ego box
        float L2 = 0.0f;
        #pragma unroll
        for (int k = 0; k < 4; ++k) {
            float cxw = alx[k] * ca - aly[k] * sa + ax;
            float cyw = alx[k] * sa + aly[k] * ca + ay;
            float dx = cxw - ex;
            float dy = cyw - ey;
            float lx =  dx * ce + dy * se;
            float ly = -dx * se + dy * ce;
            float lo = fminf(fmaxf(ef - lx, 0.0f), fmaxf(er + lx, 0.0f));
            float la = fminf(fmaxf(el - ly, 0.0f), fmaxf(ert + ly, 0.0f));
            L2 = fmaxf(L2, fminf(lo, la));
        }

        bool hit = (fmaxf(L1, L2) > 0.0f);
        any |= (hit & not_ego & (s_evalid[t] != 0) & (avalid[i] != 0));
    }

    if (any) s_any = 1;      // benign multi-writer of identical value
    __syncthreads();
    if (threadIdx.x == 0) {
        out[b] = s_any ? 0.0f : 1.0f;
    }
}

extern "C" void kernel_launch(void* const* d_in, const int* in_sizes, int n_in,
                              void* d_out, int out_size, void* d_ws, size_t ws_size,
                              hipStream_t stream) {
    const float* posg   = (const float*)d_in[0];  // infer_position (N,34,2)
    const float* headg  = (const float*)d_in[1];  // infer_heading  (N,34)
    const float* boxg   = (const float*)d_in[2];  // box            (N,4)
    const int*   validg = (const int*)  d_in[3];  // infer_valid_mask (N,34)
    // d_in[4] = batch (unused: implied by ptr blocks)
    const int*   ptrg   = (const int*)  d_in[5];  // ptr (33,)
    float* out = (float*)d_out;

    ttc_fused<<<NUM_EGO, AGENTS_PER * NSLICE, 0, stream>>>(
        posg, headg, boxg, validg, ptrg, out);
}

// Round 4
// 66.762 us; speedup vs baseline: 1.3790x; 1.0771x over previous
//
#include <hip/hip_runtime.h>
#include <math.h>

// Problem constants (match reference setup)
#define NUM_EGO    32
#define AGENTS_PER 128
#define T_TOTAL    34
#define H_OFF      4
#define TN         30           // T_TOTAL - H
#define SCALE      1.9f         // LEAST_MIN_TTC / DT = 0.95 / 0.5

// Grid: 960 blocks = (ego b, timestep t). 128 threads = one agent each.
// out is pre-set to 1.0f by a memset node; any thread that finds a
// colliding (valid) pair stores out[b] = 0.0f (benign identical-value race).
// No LDS, no __syncthreads, all loads issued up front, branch-free compute.
__global__ __launch_bounds__(AGENTS_PER) void ttc_main(
    const float* __restrict__ posg,     // (N, 34, 2)
    const float* __restrict__ headg,    // (N, 34)
    const float* __restrict__ boxg,     // (N, 4)
    const int*   __restrict__ validg,   // (N, 34) 0/1
    const int*   __restrict__ ptrg,     // (33,)
    float* __restrict__ out)            // (32,)
{
    const int blk = blockIdx.x;
    const int b   = blk / TN;           // ego index
    const int t   = blk % TN;           // relative time
    const int tt  = t + H_OFF;          // absolute time
    const int a   = threadIdx.x;        // agent slot 0..127

    const int e0 = ptrg[b];             // scalar (wave-uniform) load
    const int n  = e0 + a;

    // ---- Issue ALL global loads up front ----
    // Ego (same address across threads -> broadcast)
    const int   ev   = validg[e0 * T_TOTAL + tt];
    const float2 ep1 = *(const float2*)&posg[(e0 * T_TOTAL + tt) * 2];
    const float2 ep0 = *(const float2*)&posg[(e0 * T_TOTAL + tt - 1) * 2];
    const float eyaw = headg[e0 * T_TOTAL + tt];
    const float4 ebx = *(const float4*)&boxg[e0 * 4];
    // Agent (per-thread)
    const int   av   = validg[n * T_TOTAL + tt];
    const float2 ap1 = *(const float2*)&posg[(n * T_TOTAL + tt) * 2];
    const float2 ap0 = *(const float2*)&posg[(n * T_TOTAL + tt - 1) * 2];
    const float ayaw = headg[n * T_TOTAL + tt];
    const float4 abx = *(const float4*)&boxg[n * 4];

    // ---- Poses (TTC extrapolation) ----
    const float ex = ep1.x + SCALE * (ep1.x - ep0.x);
    const float ey = ep1.y + SCALE * (ep1.y - ep0.y);
    const float ax = ap1.x + SCALE * (ap1.x - ap0.x);
    const float ay = ap1.y + SCALE * (ap1.y - ap0.y);
    const float ce = __cosf(eyaw), se = __sinf(eyaw);
    const float ca = __cosf(ayaw), sa = __sinf(ayaw);

    const float ef = ebx.x, er = ebx.y, el = ebx.z, ert = ebx.w;
    const float af = abx.x, ar = abx.y, al = abx.z, art = abx.w;

    // local corner offsets (x: front/back, y: left/right)
    const float elx[4] = { ef,  ef, -er, -er };
    const float ely[4] = { el, -ert, -ert,  el };
    const float alx[4] = { af,  af, -ar, -ar };
    const float aly[4] = { al, -art, -art,  al };

    // L1: ego corners (world) -> agent frame vs agent box
    float L1 = 0.0f;
    #pragma unroll
    for (int k = 0; k < 4; ++k) {
        float cxw = elx[k] * ce - ely[k] * se + ex;
        float cyw = elx[k] * se + ely[k] * ce + ey;
        float dx = cxw - ax;
        float dy = cyw - ay;
        float lx =  dx * ca + dy * sa;
        float ly = -dx * sa + dy * ca;
        float lo = fminf(fmaxf(af - lx, 0.0f), fmaxf(ar + lx, 0.0f));
        float la = fminf(fmaxf(al - ly, 0.0f), fmaxf(art + ly, 0.0f));
        L1 = fmaxf(L1, fminf(lo, la));
    }

    // L2: agent corners (world) -> ego frame vs ego box
    float L2 = 0.0f;
    #pragma unroll
    for (int k = 0; k < 4; ++k) {
        float cxw = alx[k] * ca - aly[k] * sa + ax;
        float cyw = alx[k] * sa + aly[k] * ca + ay;
        float dx = cxw - ex;
        float dy = cyw - ey;
        float lx =  dx * ce + dy * se;
        float ly = -dx * se + dy * ce;
        float lo = fminf(fmaxf(ef - lx, 0.0f), fmaxf(er + lx, 0.0f));
        float la = fminf(fmaxf(el - ly, 0.0f), fmaxf(ert + ly, 0.0f));
        L2 = fmaxf(L2, fminf(lo, la));
    }

    const bool hit = (a != 0) & (ev != 0) & (av != 0) &
                     (fmaxf(L1, L2) > 0.0f);
    if (hit) {
        out[b] = 0.0f;    // benign identical-value race across threads/blocks
    }
}

extern "C" void kernel_launch(void* const* d_in, const int* in_sizes, int n_in,
                              void* d_out, int out_size, void* d_ws, size_t ws_size,
                              hipStream_t stream) {
    const float* posg   = (const float*)d_in[0];  // infer_position (N,34,2)
    const float* headg  = (const float*)d_in[1];  // infer_heading  (N,34)
    const float* boxg   = (const float*)d_in[2];  // box            (N,4)
    const int*   validg = (const int*)  d_in[3];  // infer_valid_mask (N,34)
    // d_in[4] = batch (implied by ptr blocks)
    const int*   ptrg   = (const int*)  d_in[5];  // ptr (33,)
    float* out = (float*)d_out;

    // Init out[0..31] = 1.0f via a memset node (cheaper than a kernel dispatch).
    hipMemsetD32Async((hipDeviceptr_t)out, 0x3F800000, NUM_EGO, stream);
    ttc_main<<<NUM_EGO * TN, AGENTS_PER, 0, stream>>>(
        posg, headg, boxg, validg, ptrg, out);
}

// Round 6
// 66.482 us; speedup vs baseline: 1.3848x; 1.0042x over previous
//
#include <hip/hip_runtime.h>
#include <math.h>

// Problem constants (match reference setup)
#define NUM_EGO    32
#define AGENTS_PER 128
#define T_TOTAL    34
#define H_OFF      4
#define TN         30           // T_TOTAL - H
#define SCALE      1.9f         // LEAST_MIN_TTC / DT = 0.95 / 0.5

// Grid: 960 blocks = (ego b, timestep t). 128 threads = one agent each.
// out is pre-set to 1.0f by a memset node (required: harness may zero OR
// poison d_out before launch, so the kernel cannot self-initialize with an
// idempotent atomic). Any wave that finds a colliding valid pair stores
// out[b] = 0.0f (benign identical-value race). No LDS, no __syncthreads,
// all loads issued up front, branch-free compute.
__global__ __launch_bounds__(AGENTS_PER) void ttc_main(
    const float* __restrict__ posg,     // (N, 34, 2)
    const float* __restrict__ headg,    // (N, 34)
    const float* __restrict__ boxg,     // (N, 4)
    const int*   __restrict__ validg,   // (N, 34) 0/1
    const int*   __restrict__ ptrg,     // (33,)
    float* __restrict__ out)            // (32,)
{
    const int blk = blockIdx.x;
    const int b   = blk / TN;           // ego index
    const int t   = blk % TN;           // relative time
    const int tt  = t + H_OFF;          // absolute time
    const int a   = threadIdx.x;        // agent slot 0..127

    const int e0 = ptrg[b];             // scalar (wave-uniform) load
    const int n  = e0 + a;

    // ---- Issue ALL global loads up front ----
    // Ego (same address across threads -> broadcast)
    const int   ev   = validg[e0 * T_TOTAL + tt];
    const float2 ep1 = *(const float2*)&posg[(e0 * T_TOTAL + tt) * 2];
    const float2 ep0 = *(const float2*)&posg[(e0 * T_TOTAL + tt - 1) * 2];
    const float eyaw = headg[e0 * T_TOTAL + tt];
    const float4 ebx = *(const float4*)&boxg[e0 * 4];
    // Agent (per-thread)
    const int   av   = validg[n * T_TOTAL + tt];
    const float2 ap1 = *(const float2*)&posg[(n * T_TOTAL + tt) * 2];
    const float2 ap0 = *(const float2*)&posg[(n * T_TOTAL + tt - 1) * 2];
    const float ayaw = headg[n * T_TOTAL + tt];
    const float4 abx = *(const float4*)&boxg[n * 4];

    // ---- Poses (TTC extrapolation) ----
    const float ex = ep1.x + SCALE * (ep1.x - ep0.x);
    const float ey = ep1.y + SCALE * (ep1.y - ep0.y);
    const float ax = ap1.x + SCALE * (ap1.x - ap0.x);
    const float ay = ap1.y + SCALE * (ap1.y - ap0.y);
    const float ce = __cosf(eyaw), se = __sinf(eyaw);
    const float ca = __cosf(ayaw), sa = __sinf(ayaw);

    const float ef = ebx.x, er = ebx.y, el = ebx.z, ert = ebx.w;
    const float af = abx.x, ar = abx.y, al = abx.z, art = abx.w;

    // local corner offsets (x: front/back, y: left/right)
    const float elx[4] = { ef,  ef, -er, -er };
    const float ely[4] = { el, -ert, -ert,  el };
    const float alx[4] = { af,  af, -ar, -ar };
    const float aly[4] = { al, -art, -art,  al };

    // L1: ego corners (world) -> agent frame vs agent box
    float L1 = 0.0f;
    #pragma unroll
    for (int k = 0; k < 4; ++k) {
        float cxw = elx[k] * ce - ely[k] * se + ex;
        float cyw = elx[k] * se + ely[k] * ce + ey;
        float dx = cxw - ax;
        float dy = cyw - ay;
        float lx =  dx * ca + dy * sa;
        float ly = -dx * sa + dy * ca;
        float lo = fminf(fmaxf(af - lx, 0.0f), fmaxf(ar + lx, 0.0f));
        float la = fminf(fmaxf(al - ly, 0.0f), fmaxf(art + ly, 0.0f));
        L1 = fmaxf(L1, fminf(lo, la));
    }

    // L2: agent corners (world) -> ego frame vs ego box
    float L2 = 0.0f;
    #pragma unroll
    for (int k = 0; k < 4; ++k) {
        float cxw = alx[k] * ca - aly[k] * sa + ax;
        float cyw = alx[k] * sa + aly[k] * ca + ay;
        float dx = cxw - ex;
        float dy = cyw - ey;
        float lx =  dx * ce + dy * se;
        float ly = -dx * se + dy * ce;
        float lo = fminf(fmaxf(ef - lx, 0.0f), fmaxf(er + lx, 0.0f));
        float la = fminf(fmaxf(el - ly, 0.0f), fmaxf(ert + ly, 0.0f));
        L2 = fmaxf(L2, fminf(lo, la));
    }

    const bool hit = (a != 0) & (ev != 0) & (av != 0) &
                     (fmaxf(L1, L2) > 0.0f);

    // One store per wave at most (2 waves/block), benign identical-value race.
    if (__any(hit) && (threadIdx.x & 63) == 0) {
        out[b] = 0.0f;
    }
}

extern "C" void kernel_launch(void* const* d_in, const int* in_sizes, int n_in,
                              void* d_out, int out_size, void* d_ws, size_t ws_size,
                              hipStream_t stream) {
    const float* posg   = (const float*)d_in[0];  // infer_position (N,34,2)
    const float* headg  = (const float*)d_in[1];  // infer_heading  (N,34)
    const float* boxg   = (const float*)d_in[2];  // box            (N,4)
    const int*   validg = (const int*)  d_in[3];  // infer_valid_mask (N,34)
    // d_in[4] = batch (implied by ptr blocks)
    const int*   ptrg   = (const int*)  d_in[5];  // ptr (33,)
    float* out = (float*)d_out;

    // Init out[0..31] = 1.0f via a memset node (cannot self-init in-kernel:
    // harness zeroes d_out before the correctness pass, poisons before timing).
    hipMemsetD32Async((hipDeviceptr_t)out, 0x3F800000, NUM_EGO, stream);
    ttc_main<<<NUM_EGO * TN, AGENTS_PER, 0, stream>>>(
        posg, headg, boxg, validg, ptrg, out);
}